// Round 1
// baseline (1030.279 us; speedup 1.0000x reference)
//
#include <hip/hip_runtime.h>

#define N_NODES 100000
#define EMB 64
#define N_EDGES 1280000

// ---- degree count: one thread per edge, atomic over destination ----
__global__ void deg_kernel(const int* __restrict__ dst, float* __restrict__ deg) {
    int e = blockIdx.x * blockDim.x + threadIdx.x;
    if (e < N_EDGES) atomicAdd(&deg[dst[e]], 1.0f);
}

// ---- dinv = deg^-0.5 (0 where deg==0) ----
__global__ void dinv_kernel(const float* __restrict__ deg, float* __restrict__ dinv) {
    int i = blockIdx.x * blockDim.x + threadIdx.x;
    if (i < N_NODES) {
        float d = deg[i];
        dinv[i] = (d > 0.0f) ? (1.0f / sqrtf(d)) : 0.0f;
    }
}

// ---- scatter: one wave per edge, lane d handles embedding dim d ----
// src/dst/dinv loads are wave-uniform (broadcast, 1 transaction);
// gather + atomic are 256B coalesced.
__global__ void scatter_kernel(const int* __restrict__ src, const int* __restrict__ dst,
                               const float* __restrict__ dinv,
                               const float* __restrict__ xin, float* __restrict__ xout) {
    unsigned int gid = blockIdx.x * blockDim.x + threadIdx.x;
    unsigned int e = gid >> 6;       // edge index
    unsigned int d = gid & 63u;      // embedding dim
    if (e < N_EDGES) {
        int s = src[e];
        int t = dst[e];
        float w = dinv[s] * dinv[t];
        float v = xin[(unsigned)s * EMB + d] * w;
        atomicAdd(&xout[(unsigned)t * EMB + d], v);
    }
}

// ---- out = (out + x) * scale, float4-vectorized ----
__global__ void axpy_kernel(float* __restrict__ out, const float* __restrict__ x, float scale) {
    int i = blockIdx.x * blockDim.x + threadIdx.x;
    const int n4 = N_NODES * EMB / 4;
    if (i < n4) {
        float4 o = ((const float4*)out)[i];
        float4 v = ((const float4*)x)[i];
        o.x = (o.x + v.x) * scale;
        o.y = (o.y + v.y) * scale;
        o.z = (o.z + v.z) * scale;
        o.w = (o.w + v.w) * scale;
        ((float4*)out)[i] = o;
    }
}

extern "C" void kernel_launch(void* const* d_in, const int* in_sizes, int n_in,
                              void* d_out, int out_size, void* d_ws, size_t ws_size,
                              hipStream_t stream) {
    const int*   edge = (const int*)d_in[0];        // (2, N_EDGES) row-major
    const int*   src  = edge;                       // edge_index[0]
    const int*   dst  = edge + N_EDGES;             // edge_index[1]
    const float* emb  = (const float*)d_in[1];      // (N_NODES, 64) fp32
    float*       out  = (float*)d_out;

    // workspace carve (all 16B-aligned offsets)
    char*  ws   = (char*)d_ws;
    float* deg  = (float*)(ws);                              // 400 KB
    float* dinv = (float*)(ws + 400000);                     // 400 KB
    float* xA   = (float*)(ws + 800000);                     // 25.6 MB
    float* xB   = (float*)(ws + 800000 + 25600000);          // 25.6 MB

    const size_t xbytes = (size_t)N_NODES * EMB * sizeof(float);

    // degree + norm
    hipMemsetAsync(deg, 0, (size_t)N_NODES * sizeof(float), stream);
    deg_kernel<<<(N_EDGES + 255) / 256, 256, 0, stream>>>(dst, deg);
    dinv_kernel<<<(N_NODES + 255) / 256, 256, 0, stream>>>(deg, dinv);

    // out = emb  (accumulator init; d_out is re-poisoned before every call)
    hipMemcpyAsync(out, emb, xbytes, hipMemcpyDeviceToDevice, stream);

    const float* xin = emb;
    float* bufs[2] = {xA, xB};
    const unsigned int scatter_threads = (unsigned int)N_EDGES * 64u;
    for (int l = 0; l < 3; ++l) {
        float* xout = bufs[l & 1];
        hipMemsetAsync(xout, 0, xbytes, stream);
        scatter_kernel<<<(scatter_threads + 255) / 256, 256, 0, stream>>>(src, dst, dinv, xin, xout);
        float scale = (l == 2) ? 0.25f : 1.0f;
        axpy_kernel<<<(N_NODES * EMB / 4 + 255) / 256, 256, 0, stream>>>(out, xout, scale);
        xin = xout;
    }
}

// Round 2
// 494.722 us; speedup vs baseline: 2.0825x; 2.0825x over previous
//
#include <hip/hip_runtime.h>

#define N_NODES 100000
#define EMB 64
#define N_EDGES 1280000
#define SCAN_TILE 1024  // nodes per scan block (256 threads x 4)

// ---- degree count over destinations (int, exact) ----
__global__ void deg_kernel(const int* __restrict__ dst, int* __restrict__ deg) {
    int e = blockIdx.x * blockDim.x + threadIdx.x;
    if (e < N_EDGES) atomicAdd(&deg[dst[e]], 1);
}

// ---- dinv = deg^-0.5 (0 where deg==0) ----
__global__ void dinv_kernel(const int* __restrict__ deg, float* __restrict__ dinv) {
    int i = blockIdx.x * blockDim.x + threadIdx.x;
    if (i < N_NODES) {
        int d = deg[i];
        dinv[i] = (d > 0) ? rsqrtf((float)d) : 0.0f;
    }
}

// ---- scan pass 1: per-block local exclusive scan + block sums ----
__global__ void scan1_kernel(const int* __restrict__ deg, int* __restrict__ local_scan,
                             int* __restrict__ block_sums) {
    __shared__ int lds[256];
    int base = blockIdx.x * SCAN_TILE;
    int vals[4];
    int tsum = 0;
#pragma unroll
    for (int k = 0; k < 4; ++k) {
        int i = base + threadIdx.x * 4 + k;
        vals[k] = (i < N_NODES) ? deg[i] : 0;
        tsum += vals[k];
    }
    lds[threadIdx.x] = tsum;
    __syncthreads();
    // Hillis-Steele inclusive scan of thread sums
    for (int off = 1; off < 256; off <<= 1) {
        int v = (threadIdx.x >= (unsigned)off) ? lds[threadIdx.x - off] : 0;
        __syncthreads();
        lds[threadIdx.x] += v;
        __syncthreads();
    }
    int texcl = lds[threadIdx.x] - tsum;  // exclusive prefix of this thread
    if (threadIdx.x == 255) block_sums[blockIdx.x] = lds[255];
    int run = texcl;
#pragma unroll
    for (int k = 0; k < 4; ++k) {
        int i = base + threadIdx.x * 4 + k;
        if (i < N_NODES) local_scan[i] = run;
        run += vals[k];
    }
}

// ---- scan pass 2: exclusive scan of the 98 block sums (single block) ----
__global__ void scan2_kernel(int* __restrict__ block_sums, int nb) {
    __shared__ int lds[128];
    int v = (threadIdx.x < (unsigned)nb) ? block_sums[threadIdx.x] : 0;
    lds[threadIdx.x] = v;
    __syncthreads();
    for (int off = 1; off < 128; off <<= 1) {
        int t = (threadIdx.x >= (unsigned)off) ? lds[threadIdx.x - off] : 0;
        __syncthreads();
        lds[threadIdx.x] += t;
        __syncthreads();
    }
    if (threadIdx.x < (unsigned)nb) block_sums[threadIdx.x] = lds[threadIdx.x] - v;
}

// ---- scan pass 3: add block offsets; init cursor; cap row_start ----
__global__ void scan3_kernel(int* __restrict__ row_start, const int* __restrict__ block_sums,
                             int* __restrict__ cursor) {
    int i = blockIdx.x * blockDim.x + threadIdx.x;
    if (i < N_NODES) {
        int v = row_start[i] + block_sums[i / SCAN_TILE];
        row_start[i] = v;
        cursor[i] = v;
    }
    if (i == 0) row_start[N_NODES] = N_EDGES;
}

// ---- CSR fill: counting-sort edges by destination ----
__global__ void fill_kernel(const int* __restrict__ src, const int* __restrict__ dst,
                            int* __restrict__ cursor, int* __restrict__ col) {
    int e = blockIdx.x * blockDim.x + threadIdx.x;
    if (e < N_EDGES) {
        int t = dst[e];
        int pos = atomicAdd(&cursor[t], 1);
        col[pos] = src[e];
    }
}

// ---- propagation: one wave per destination row, lane = embedding dim ----
// acc = dinv[row] * sum_e dinv[col_e] * xin[col_e]; fused out-accumulate.
__global__ void gather_kernel(const int* __restrict__ row_start, const int* __restrict__ col,
                              const float* __restrict__ dinv,
                              const float* __restrict__ xin, float* __restrict__ xout,
                              float* __restrict__ out, float scale) {
    unsigned int gid = blockIdx.x * blockDim.x + threadIdx.x;
    unsigned int row = gid >> 6;
    unsigned int d = gid & 63u;
    if (row >= N_NODES) return;
    int beg = row_start[row];
    int end = row_start[row + 1];
    float acc = 0.0f;
    int e = beg;
    for (; e + 1 < end; e += 2) {  // 2-wide for MLP
        int c0 = col[e];
        int c1 = col[e + 1];
        float w0 = dinv[c0];
        float w1 = dinv[c1];
        float v0 = xin[(unsigned)c0 * EMB + d];
        float v1 = xin[(unsigned)c1 * EMB + d];
        acc += w0 * v0;
        acc += w1 * v1;
    }
    if (e < end) {
        int c = col[e];
        acc += dinv[c] * xin[(unsigned)c * EMB + d];
    }
    acc *= dinv[row];
    unsigned int o = row * EMB + d;
    xout[o] = acc;
    out[o] = (out[o] + acc) * scale;
}

extern "C" void kernel_launch(void* const* d_in, const int* in_sizes, int n_in,
                              void* d_out, int out_size, void* d_ws, size_t ws_size,
                              hipStream_t stream) {
    const int*   edge = (const int*)d_in[0];   // (2, N_EDGES) row-major
    const int*   src  = edge;
    const int*   dst  = edge + N_EDGES;
    const float* emb  = (const float*)d_in[1]; // (N_NODES, 64) fp32
    float*       out  = (float*)d_out;

    // workspace carve (16B-aligned offsets), ~57.5 MB total
    char* ws = (char*)d_ws;
    size_t off = 0;
    int* deg       = (int*)(ws + off); off += 400000;            // reused as cursor
    int* row_start = (int*)(ws + off); off += 400016;            // N_NODES+1 ints
    int* bsums     = (int*)(ws + off); off += 512;
    float* dinv    = (float*)(ws + off); off += 400000;
    int* col       = (int*)(ws + off); off += (size_t)N_EDGES * 4;   // 5.12 MB
    float* xA      = (float*)(ws + off); off += (size_t)N_NODES * EMB * 4;  // 25.6 MB
    float* xB      = (float*)(ws + off); off += (size_t)N_NODES * EMB * 4;  // 25.6 MB

    const size_t xbytes = (size_t)N_NODES * EMB * sizeof(float);
    const int NB = (N_NODES + SCAN_TILE - 1) / SCAN_TILE;  // 98

    // ---- CSR build ----
    hipMemsetAsync(deg, 0, (size_t)N_NODES * sizeof(int), stream);
    deg_kernel<<<(N_EDGES + 255) / 256, 256, 0, stream>>>(dst, deg);
    dinv_kernel<<<(N_NODES + 255) / 256, 256, 0, stream>>>(deg, dinv);
    scan1_kernel<<<NB, 256, 0, stream>>>(deg, row_start, bsums);
    scan2_kernel<<<1, 128, 0, stream>>>(bsums, NB);
    scan3_kernel<<<(N_NODES + 255) / 256, 256, 0, stream>>>(row_start, bsums, deg /*cursor*/);
    fill_kernel<<<(N_EDGES + 255) / 256, 256, 0, stream>>>(src, dst, deg /*cursor*/, col);

    // ---- out = emb ----
    hipMemcpyAsync(out, emb, xbytes, hipMemcpyDeviceToDevice, stream);

    // ---- 3 propagation layers, fused accumulate ----
    const unsigned int gthreads = (unsigned int)N_NODES * EMB;
    const int gblocks = (int)((gthreads + 255) / 256);
    gather_kernel<<<gblocks, 256, 0, stream>>>(row_start, col, dinv, emb, xA, out, 1.0f);
    gather_kernel<<<gblocks, 256, 0, stream>>>(row_start, col, dinv, xA, xB, out, 1.0f);
    gather_kernel<<<gblocks, 256, 0, stream>>>(row_start, col, dinv, xB, xA, out, 0.25f);
}

// Round 5
// 490.466 us; speedup vs baseline: 2.1006x; 1.0087x over previous
//
#include <hip/hip_runtime.h>

#define N_NODES 100000
#define EMB 64
#define N_EDGES 1280000
#define SCAN_TILE 1024  // nodes per scan block (256 threads x 4)

typedef unsigned long long u64;

// pack (src, weight) into one 64b word: low 32 = src index, high 32 = float bits
__device__ __forceinline__ u64 pack_cw(unsigned s, float w) {
    return (u64)s | ((u64)__float_as_uint(w) << 32);
}

// ---- degree count over destinations, 4 edges/thread (N_EDGES % 4 == 0) ----
__global__ void deg_kernel(const int* __restrict__ dst, int* __restrict__ deg) {
    int t = blockIdx.x * blockDim.x + threadIdx.x;
    int e = t * 4;
    if (e + 3 < N_EDGES) {
        int4 d4 = *(const int4*)(dst + e);
        atomicAdd(&deg[d4.x], 1);
        atomicAdd(&deg[d4.y], 1);
        atomicAdd(&deg[d4.z], 1);
        atomicAdd(&deg[d4.w], 1);
    }
}

// ---- dinv = deg^-0.5 (0 where deg==0) ----
__global__ void dinv_kernel(const int* __restrict__ deg, float* __restrict__ dinv) {
    int i = blockIdx.x * blockDim.x + threadIdx.x;
    if (i < N_NODES) {
        int d = deg[i];
        dinv[i] = (d > 0) ? rsqrtf((float)d) : 0.0f;
    }
}

// ---- scan pass 1: per-block local exclusive scan + block sums ----
__global__ void scan1_kernel(const int* __restrict__ deg, int* __restrict__ local_scan,
                             int* __restrict__ block_sums) {
    __shared__ int lds[256];
    int base = blockIdx.x * SCAN_TILE;
    int vals[4];
    int tsum = 0;
#pragma unroll
    for (int k = 0; k < 4; ++k) {
        int i = base + threadIdx.x * 4 + k;
        vals[k] = (i < N_NODES) ? deg[i] : 0;
        tsum += vals[k];
    }
    lds[threadIdx.x] = tsum;
    __syncthreads();
    for (int off = 1; off < 256; off <<= 1) {
        int v = (threadIdx.x >= (unsigned)off) ? lds[threadIdx.x - off] : 0;
        __syncthreads();
        lds[threadIdx.x] += v;
        __syncthreads();
    }
    int texcl = lds[threadIdx.x] - tsum;
    if (threadIdx.x == 255) block_sums[blockIdx.x] = lds[255];
    int run = texcl;
#pragma unroll
    for (int k = 0; k < 4; ++k) {
        int i = base + threadIdx.x * 4 + k;
        if (i < N_NODES) local_scan[i] = run;
        run += vals[k];
    }
}

// ---- scan pass 2: exclusive scan of the 98 block sums (single block) ----
__global__ void scan2_kernel(int* __restrict__ block_sums, int nb) {
    __shared__ int lds[128];
    int v = (threadIdx.x < (unsigned)nb) ? block_sums[threadIdx.x] : 0;
    lds[threadIdx.x] = v;
    __syncthreads();
    for (int off = 1; off < 128; off <<= 1) {
        int t = (threadIdx.x >= (unsigned)off) ? lds[threadIdx.x - off] : 0;
        __syncthreads();
        lds[threadIdx.x] += t;
        __syncthreads();
    }
    if (threadIdx.x < (unsigned)nb) block_sums[threadIdx.x] = lds[threadIdx.x] - v;
}

// ---- scan pass 3: add block offsets; init cursor; cap row_start ----
__global__ void scan3_kernel(int* __restrict__ row_start, const int* __restrict__ block_sums,
                             int* __restrict__ cursor) {
    int i = blockIdx.x * blockDim.x + threadIdx.x;
    if (i < N_NODES) {
        int v = row_start[i] + block_sums[i / SCAN_TILE];
        row_start[i] = v;
        cursor[i] = v;
    }
    if (i == 0) row_start[N_NODES] = N_EDGES;
}

// ---- CSR fill: counting-sort edges by dst, writing packed (src, dinv[src]) ----
__global__ void fill_kernel(const int* __restrict__ src, const int* __restrict__ dst,
                            const float* __restrict__ dinv,
                            int* __restrict__ cursor, u64* __restrict__ colw) {
    int t = blockIdx.x * blockDim.x + threadIdx.x;
    int e = t * 4;
    if (e + 3 < N_EDGES) {
        int4 s4 = *(const int4*)(src + e);
        int4 d4 = *(const int4*)(dst + e);
        int p0 = atomicAdd(&cursor[d4.x], 1);
        int p1 = atomicAdd(&cursor[d4.y], 1);
        int p2 = atomicAdd(&cursor[d4.z], 1);
        int p3 = atomicAdd(&cursor[d4.w], 1);
        float w0 = dinv[s4.x], w1 = dinv[s4.y], w2 = dinv[s4.z], w3 = dinv[s4.w];
        __builtin_nontemporal_store(pack_cw((unsigned)s4.x, w0), &colw[p0]);
        __builtin_nontemporal_store(pack_cw((unsigned)s4.y, w1), &colw[p1]);
        __builtin_nontemporal_store(pack_cw((unsigned)s4.z, w2), &colw[p2]);
        __builtin_nontemporal_store(pack_cw((unsigned)s4.w, w3), &colw[p3]);
    }
}

// ---- propagation: one wave per destination row, lane = embedding dim ----
// acc = dinv[row] * sum_e w_e * xin[c_e]; fused out-accumulate with prior.
template <bool WRITE_X>
__global__ void gather_kernel(const int* __restrict__ row_start, const u64* __restrict__ colw,
                              const float* __restrict__ dinv,
                              const float* __restrict__ xin, float* __restrict__ xout,
                              const float* __restrict__ prior, float* __restrict__ out,
                              float scale) {
    unsigned int gid = blockIdx.x * blockDim.x + threadIdx.x;
    unsigned int row = gid >> 6;
    unsigned int d = gid & 63u;
    if (row >= N_NODES) return;
    int beg = row_start[row];
    int end = row_start[row + 1];
    float acc = 0.0f;
    int e = beg;
    for (; e + 3 < end; e += 4) {  // 4 outstanding gathers per body
        u64 p0 = __builtin_nontemporal_load(&colw[e]);
        u64 p1 = __builtin_nontemporal_load(&colw[e + 1]);
        u64 p2 = __builtin_nontemporal_load(&colw[e + 2]);
        u64 p3 = __builtin_nontemporal_load(&colw[e + 3]);
        float v0 = xin[(unsigned)(p0 & 0xffffffffu) * EMB + d];
        float v1 = xin[(unsigned)(p1 & 0xffffffffu) * EMB + d];
        float v2 = xin[(unsigned)(p2 & 0xffffffffu) * EMB + d];
        float v3 = xin[(unsigned)(p3 & 0xffffffffu) * EMB + d];
        acc += __uint_as_float((unsigned)(p0 >> 32)) * v0;
        acc += __uint_as_float((unsigned)(p1 >> 32)) * v1;
        acc += __uint_as_float((unsigned)(p2 >> 32)) * v2;
        acc += __uint_as_float((unsigned)(p3 >> 32)) * v3;
    }
    for (; e < end; ++e) {
        u64 p = __builtin_nontemporal_load(&colw[e]);
        acc += __uint_as_float((unsigned)(p >> 32)) * xin[(unsigned)(p & 0xffffffffu) * EMB + d];
    }
    acc *= dinv[row];
    unsigned int o = row * EMB + d;
    if (WRITE_X) __builtin_nontemporal_store(acc, &xout[o]);
    float pr = __builtin_nontemporal_load(&prior[o]);
    __builtin_nontemporal_store((pr + acc) * scale, &out[o]);
}

extern "C" void kernel_launch(void* const* d_in, const int* in_sizes, int n_in,
                              void* d_out, int out_size, void* d_ws, size_t ws_size,
                              hipStream_t stream) {
    const int*   edge = (const int*)d_in[0];   // (2, N_EDGES) row-major
    const int*   src  = edge;
    const int*   dst  = edge + N_EDGES;
    const float* emb  = (const float*)d_in[1]; // (N_NODES, 64) fp32
    float*       out  = (float*)d_out;

    // workspace carve (16B-aligned offsets), ~62.7 MB total
    char* ws = (char*)d_ws;
    size_t off = 0;
    int* deg       = (int*)(ws + off); off += 400000;  // reused as cursor
    int* row_start = (int*)(ws + off); off += 400016;
    int* bsums     = (int*)(ws + off); off += 512;
    float* dinv    = (float*)(ws + off); off += 400000;
    u64* colw      = (u64*)(ws + off); off += (size_t)N_EDGES * 8;        // 10.24 MB
    float* xA      = (float*)(ws + off); off += (size_t)N_NODES * EMB * 4; // 25.6 MB
    float* xB      = (float*)(ws + off); off += (size_t)N_NODES * EMB * 4; // 25.6 MB

    const int NB = (N_NODES + SCAN_TILE - 1) / SCAN_TILE;  // 98

    // ---- CSR build (once per call; reused by all 3 layers) ----
    hipMemsetAsync(deg, 0, (size_t)N_NODES * sizeof(int), stream);
    deg_kernel<<<(N_EDGES / 4 + 255) / 256, 256, 0, stream>>>(dst, deg);
    dinv_kernel<<<(N_NODES + 255) / 256, 256, 0, stream>>>(deg, dinv);
    scan1_kernel<<<NB, 256, 0, stream>>>(deg, row_start, bsums);
    scan2_kernel<<<1, 128, 0, stream>>>(bsums, NB);
    scan3_kernel<<<(N_NODES + 255) / 256, 256, 0, stream>>>(row_start, bsums, deg /*cursor*/);
    fill_kernel<<<(N_EDGES / 4 + 255) / 256, 256, 0, stream>>>(src, dst, dinv, deg /*cursor*/, colw);

    // ---- 3 propagation layers; out accumulation fused (layer 1 seeds from emb) ----
    const unsigned int gthreads = (unsigned int)N_NODES * EMB;
    const int gblocks = (int)((gthreads + 255) / 256);
    gather_kernel<true><<<gblocks, 256, 0, stream>>>(row_start, colw, dinv, emb, xA, emb, out, 1.0f);
    gather_kernel<true><<<gblocks, 256, 0, stream>>>(row_start, colw, dinv, xA, xB, out, out, 1.0f);
    gather_kernel<false><<<gblocks, 256, 0, stream>>>(row_start, colw, dinv, xB, xA, out, out, 0.25f);
}

// Round 6
// 386.959 us; speedup vs baseline: 2.6625x; 1.2675x over previous
//
#include <hip/hip_runtime.h>

#define N_NODES 100000
#define EMB 64
#define N_EDGES 1280000
#define SCAN_TILE 1024  // nodes per scan block (256 threads x 4)

typedef unsigned long long u64;
typedef _Float16 f16;

// pack (src, weight) into one 64b word: low 32 = src index, high 32 = float bits
__device__ __forceinline__ u64 pack_cw(unsigned s, float w) {
    return (u64)s | ((u64)__float_as_uint(w) << 32);
}

// ---- degree count over destinations, 4 edges/thread (N_EDGES % 4 == 0) ----
__global__ void deg_kernel(const int* __restrict__ dst, int* __restrict__ deg) {
    int t = blockIdx.x * blockDim.x + threadIdx.x;
    int e = t * 4;
    if (e + 3 < N_EDGES) {
        int4 d4 = *(const int4*)(dst + e);
        atomicAdd(&deg[d4.x], 1);
        atomicAdd(&deg[d4.y], 1);
        atomicAdd(&deg[d4.z], 1);
        atomicAdd(&deg[d4.w], 1);
    }
}

// ---- dinv = deg^-0.5 (0 where deg==0) ----
__global__ void dinv_kernel(const int* __restrict__ deg, float* __restrict__ dinv) {
    int i = blockIdx.x * blockDim.x + threadIdx.x;
    if (i < N_NODES) {
        int d = deg[i];
        dinv[i] = (d > 0) ? rsqrtf((float)d) : 0.0f;
    }
}

// ---- emb (fp32) -> x0 (fp16), 4 elems/thread ----
__global__ void half_kernel(const float* __restrict__ emb, f16* __restrict__ xh) {
    int i = blockIdx.x * blockDim.x + threadIdx.x;
    const int n4 = N_NODES * EMB / 4;
    if (i < n4) {
        float4 v = ((const float4*)emb)[i];
        f16 h[4] = {(f16)v.x, (f16)v.y, (f16)v.z, (f16)v.w};
        ((u64*)xh)[i] = *(const u64*)h;
    }
}

// ---- scan pass 1: per-block local exclusive scan + block sums ----
__global__ void scan1_kernel(const int* __restrict__ deg, int* __restrict__ local_scan,
                             int* __restrict__ block_sums) {
    __shared__ int lds[256];
    int base = blockIdx.x * SCAN_TILE;
    int vals[4];
    int tsum = 0;
#pragma unroll
    for (int k = 0; k < 4; ++k) {
        int i = base + threadIdx.x * 4 + k;
        vals[k] = (i < N_NODES) ? deg[i] : 0;
        tsum += vals[k];
    }
    lds[threadIdx.x] = tsum;
    __syncthreads();
    for (int off = 1; off < 256; off <<= 1) {
        int v = (threadIdx.x >= (unsigned)off) ? lds[threadIdx.x - off] : 0;
        __syncthreads();
        lds[threadIdx.x] += v;
        __syncthreads();
    }
    int texcl = lds[threadIdx.x] - tsum;
    if (threadIdx.x == 255) block_sums[blockIdx.x] = lds[255];
    int run = texcl;
#pragma unroll
    for (int k = 0; k < 4; ++k) {
        int i = base + threadIdx.x * 4 + k;
        if (i < N_NODES) local_scan[i] = run;
        run += vals[k];
    }
}

// ---- scan pass 2: exclusive scan of the 98 block sums (single block) ----
__global__ void scan2_kernel(int* __restrict__ block_sums, int nb) {
    __shared__ int lds[128];
    int v = (threadIdx.x < (unsigned)nb) ? block_sums[threadIdx.x] : 0;
    lds[threadIdx.x] = v;
    __syncthreads();
    for (int off = 1; off < 128; off <<= 1) {
        int t = (threadIdx.x >= (unsigned)off) ? lds[threadIdx.x - off] : 0;
        __syncthreads();
        lds[threadIdx.x] += t;
        __syncthreads();
    }
    if (threadIdx.x < (unsigned)nb) block_sums[threadIdx.x] = lds[threadIdx.x] - v;
}

// ---- scan pass 3: add block offsets; init cursor; cap row_start ----
__global__ void scan3_kernel(int* __restrict__ row_start, const int* __restrict__ block_sums,
                             int* __restrict__ cursor) {
    int i = blockIdx.x * blockDim.x + threadIdx.x;
    if (i < N_NODES) {
        int v = row_start[i] + block_sums[i / SCAN_TILE];
        row_start[i] = v;
        cursor[i] = v;
    }
    if (i == 0) row_start[N_NODES] = N_EDGES;
}

// ---- CSR fill: counting-sort edges by dst, writing packed (src, dinv[src]) ----
__global__ void fill_kernel(const int* __restrict__ src, const int* __restrict__ dst,
                            const float* __restrict__ dinv,
                            int* __restrict__ cursor, u64* __restrict__ colw) {
    int t = blockIdx.x * blockDim.x + threadIdx.x;
    int e = t * 4;
    if (e + 3 < N_EDGES) {
        int4 s4 = *(const int4*)(src + e);
        int4 d4 = *(const int4*)(dst + e);
        int p0 = atomicAdd(&cursor[d4.x], 1);
        int p1 = atomicAdd(&cursor[d4.y], 1);
        int p2 = atomicAdd(&cursor[d4.z], 1);
        int p3 = atomicAdd(&cursor[d4.w], 1);
        float w0 = dinv[s4.x], w1 = dinv[s4.y], w2 = dinv[s4.z], w3 = dinv[s4.w];
        __builtin_nontemporal_store(pack_cw((unsigned)s4.x, w0), &colw[p0]);
        __builtin_nontemporal_store(pack_cw((unsigned)s4.y, w1), &colw[p1]);
        __builtin_nontemporal_store(pack_cw((unsigned)s4.z, w2), &colw[p2]);
        __builtin_nontemporal_store(pack_cw((unsigned)s4.w, w3), &colw[p3]);
    }
}

// ---- propagation: one wave per destination row, lane = embedding dim ----
// Lane-parallel colw fetch (one 8B/lane load covers the row), __shfl broadcast
// per edge, fp16 gathers (128B/wave), fp32 accumulate.
// FINAL layer fuses out = (emb + x1 + x2 + acc) * 0.25.
template <bool FINAL>
__global__ void gather_kernel(const int* __restrict__ row_start, const u64* __restrict__ colw,
                              const float* __restrict__ dinv,
                              const f16* __restrict__ xin, f16* __restrict__ xout,
                              const float* __restrict__ emb,
                              const f16* __restrict__ x1, const f16* __restrict__ x2,
                              float* __restrict__ out) {
    unsigned int gid = blockIdx.x * blockDim.x + threadIdx.x;
    unsigned int row = gid >> 6;
    int d = (int)(gid & 63u);  // lane == embedding dim
    if (row >= N_NODES) return;
    int beg = row_start[row];
    int end = row_start[row + 1];
    float acc = 0.0f;
    for (int cb = beg; cb < end; cb += 64) {
        // lane l holds edge cb+l of this row (clamped; excess lanes unused)
        int idx = cb + d;
        u64 pv = colw[idx < N_EDGES ? idx : (N_EDGES - 1)];
        unsigned ci = (unsigned)(pv & 0xffffffffu);
        float wi = __uint_as_float((unsigned)(pv >> 32));
        int n = end - cb;
        if (n > 64) n = 64;
        int k = 0;
        for (; k + 3 < n; k += 4) {
            unsigned c0 = (unsigned)__shfl((int)ci, k);
            unsigned c1 = (unsigned)__shfl((int)ci, k + 1);
            unsigned c2 = (unsigned)__shfl((int)ci, k + 2);
            unsigned c3 = (unsigned)__shfl((int)ci, k + 3);
            float w0 = __shfl(wi, k);
            float w1 = __shfl(wi, k + 1);
            float w2 = __shfl(wi, k + 2);
            float w3 = __shfl(wi, k + 3);
            float v0 = (float)xin[c0 * EMB + d];
            float v1 = (float)xin[c1 * EMB + d];
            float v2 = (float)xin[c2 * EMB + d];
            float v3 = (float)xin[c3 * EMB + d];
            acc += w0 * v0;
            acc += w1 * v1;
            acc += w2 * v2;
            acc += w3 * v3;
        }
        for (; k < n; ++k) {
            unsigned c = (unsigned)__shfl((int)ci, k);
            float w = __shfl(wi, k);
            acc += w * (float)xin[c * EMB + d];
        }
    }
    acc *= dinv[row];
    unsigned int o = row * EMB + (unsigned)d;
    if (!FINAL) {
        __builtin_nontemporal_store((f16)acc, &xout[o]);
    } else {
        float r = (emb[o] + (float)x1[o] + (float)x2[o] + acc) * 0.25f;
        __builtin_nontemporal_store(r, &out[o]);
    }
}

extern "C" void kernel_launch(void* const* d_in, const int* in_sizes, int n_in,
                              void* d_out, int out_size, void* d_ws, size_t ws_size,
                              hipStream_t stream) {
    const int*   edge = (const int*)d_in[0];   // (2, N_EDGES) row-major
    const int*   src  = edge;
    const int*   dst  = edge + N_EDGES;
    const float* emb  = (const float*)d_in[1]; // (N_NODES, 64) fp32
    float*       out  = (float*)d_out;

    // workspace carve (16B-aligned offsets), ~50 MB total
    char* ws = (char*)d_ws;
    size_t off = 0;
    int* deg       = (int*)(ws + off); off += 400000;  // reused as cursor
    int* row_start = (int*)(ws + off); off += 400016;
    int* bsums     = (int*)(ws + off); off += 512;
    float* dinv    = (float*)(ws + off); off += 400000;
    u64* colw      = (u64*)(ws + off); off += (size_t)N_EDGES * 8;         // 10.24 MB
    f16* x0h       = (f16*)(ws + off); off += (size_t)N_NODES * EMB * 2;   // 12.8 MB
    f16* x1h       = (f16*)(ws + off); off += (size_t)N_NODES * EMB * 2;   // 12.8 MB
    f16* x2h       = (f16*)(ws + off); off += (size_t)N_NODES * EMB * 2;   // 12.8 MB

    const int NB = (N_NODES + SCAN_TILE - 1) / SCAN_TILE;  // 98

    // ---- CSR build (once per call; reused by all 3 layers) ----
    hipMemsetAsync(deg, 0, (size_t)N_NODES * sizeof(int), stream);
    deg_kernel<<<(N_EDGES / 4 + 255) / 256, 256, 0, stream>>>(dst, deg);
    dinv_kernel<<<(N_NODES + 255) / 256, 256, 0, stream>>>(deg, dinv);
    scan1_kernel<<<NB, 256, 0, stream>>>(deg, row_start, bsums);
    scan2_kernel<<<1, 128, 0, stream>>>(bsums, NB);
    scan3_kernel<<<(N_NODES + 255) / 256, 256, 0, stream>>>(row_start, bsums, deg /*cursor*/);
    fill_kernel<<<(N_EDGES / 4 + 255) / 256, 256, 0, stream>>>(src, dst, dinv, deg /*cursor*/, colw);

    // ---- emb -> fp16 ----
    half_kernel<<<(N_NODES * EMB / 4 + 255) / 256, 256, 0, stream>>>(emb, x0h);

    // ---- 3 propagation layers (fp16 x), final fuses the 1/4-sum ----
    const unsigned int gthreads = (unsigned int)N_NODES * EMB;
    const int gblocks = (int)((gthreads + 255) / 256);
    gather_kernel<false><<<gblocks, 256, 0, stream>>>(row_start, colw, dinv, x0h, x1h,
                                                      emb, x1h, x2h, out);
    gather_kernel<false><<<gblocks, 256, 0, stream>>>(row_start, colw, dinv, x1h, x2h,
                                                      emb, x1h, x2h, out);
    gather_kernel<true><<<gblocks, 256, 0, stream>>>(row_start, colw, dinv, x2h, (f16*)0,
                                                     emb, x1h, x2h, out);
}

// Round 7
// 355.567 us; speedup vs baseline: 2.8976x; 1.0883x over previous
//
#include <hip/hip_runtime.h>

#define N_NODES 100000
#define EMB 64
#define N_EDGES 1280000
#define SCAN_TILE 1024   // nodes per scan block (256 threads x 4)
#define NPART 8          // node partitions == XCD count (blockIdx%8 affinity heuristic)
#define PART_NODES 12500 // N_NODES / NPART
#define FILL_EPB 1024    // edges per fill block (256 threads x 4); N_EDGES % 1024 == 0

typedef unsigned long long u64;
typedef _Float16 f16;

// pack (src, weight) into one 64b word: low 32 = src index, high 32 = float bits
__device__ __forceinline__ u64 pack_cw(unsigned s, float w) {
    return (u64)s | ((u64)__float_as_uint(w) << 32);
}

// ---- degree count over destinations, 4 edges/thread (N_EDGES % 4 == 0) ----
__global__ void deg_kernel(const int* __restrict__ dst, int* __restrict__ deg) {
    int t = blockIdx.x * blockDim.x + threadIdx.x;
    int e = t * 4;
    if (e + 3 < N_EDGES) {
        int4 d4 = *(const int4*)(dst + e);
        atomicAdd(&deg[d4.x], 1);
        atomicAdd(&deg[d4.y], 1);
        atomicAdd(&deg[d4.z], 1);
        atomicAdd(&deg[d4.w], 1);
    }
}

// ---- dinv = deg^-0.5 (0 where deg==0) ----
__global__ void dinv_kernel(const int* __restrict__ deg, float* __restrict__ dinv) {
    int i = blockIdx.x * blockDim.x + threadIdx.x;
    if (i < N_NODES) {
        int d = deg[i];
        dinv[i] = (d > 0) ? rsqrtf((float)d) : 0.0f;
    }
}

// ---- emb (fp32) -> x0 (fp16), 4 elems/thread ----
__global__ void half_kernel(const float* __restrict__ emb, f16* __restrict__ xh) {
    int i = blockIdx.x * blockDim.x + threadIdx.x;
    const int n4 = N_NODES * EMB / 4;
    if (i < n4) {
        float4 v = ((const float4*)emb)[i];
        f16 h[4] = {(f16)v.x, (f16)v.y, (f16)v.z, (f16)v.w};
        ((u64*)xh)[i] = *(const u64*)h;
    }
}

// ---- scan pass 1: per-block local exclusive scan + block sums ----
__global__ void scan1_kernel(const int* __restrict__ deg, int* __restrict__ local_scan,
                             int* __restrict__ block_sums) {
    __shared__ int lds[256];
    int base = blockIdx.x * SCAN_TILE;
    int vals[4];
    int tsum = 0;
#pragma unroll
    for (int k = 0; k < 4; ++k) {
        int i = base + threadIdx.x * 4 + k;
        vals[k] = (i < N_NODES) ? deg[i] : 0;
        tsum += vals[k];
    }
    lds[threadIdx.x] = tsum;
    __syncthreads();
    for (int off = 1; off < 256; off <<= 1) {
        int v = (threadIdx.x >= (unsigned)off) ? lds[threadIdx.x - off] : 0;
        __syncthreads();
        lds[threadIdx.x] += v;
        __syncthreads();
    }
    int texcl = lds[threadIdx.x] - tsum;
    if (threadIdx.x == 255) block_sums[blockIdx.x] = lds[255];
    int run = texcl;
#pragma unroll
    for (int k = 0; k < 4; ++k) {
        int i = base + threadIdx.x * 4 + k;
        if (i < N_NODES) local_scan[i] = run;
        run += vals[k];
    }
}

// ---- scan pass 2: exclusive scan of the 98 block sums (single block) ----
__global__ void scan2_kernel(int* __restrict__ block_sums, int nb) {
    __shared__ int lds[128];
    int v = (threadIdx.x < (unsigned)nb) ? block_sums[threadIdx.x] : 0;
    lds[threadIdx.x] = v;
    __syncthreads();
    for (int off = 1; off < 128; off <<= 1) {
        int t = (threadIdx.x >= (unsigned)off) ? lds[threadIdx.x - off] : 0;
        __syncthreads();
        lds[threadIdx.x] += t;
        __syncthreads();
    }
    if (threadIdx.x < (unsigned)nb) block_sums[threadIdx.x] = lds[threadIdx.x] - v;
}

// ---- scan pass 3: add block offsets; init cursor; cap row_start ----
__global__ void scan3_kernel(int* __restrict__ row_start, const int* __restrict__ block_sums,
                             int* __restrict__ cursor) {
    int i = blockIdx.x * blockDim.x + threadIdx.x;
    if (i < N_NODES) {
        int v = row_start[i] + block_sums[i / SCAN_TILE];
        row_start[i] = v;
        cursor[i] = v;
    }
    if (i == 0) row_start[N_NODES] = N_EDGES;
}

// ---- partition-affine CSR fill ----
// Block b: partition p = b % 8 (maps to XCD p under round-robin dispatch),
// edge chunk c = b / 8. Writes only edges with dst in [p*12500, (p+1)*12500):
// all of partition p's colw lines are assembled in one XCD's L2 -> one
// writeback per line instead of ~8 cross-XCD partial writebacks.
__global__ void fill_part_kernel(const int* __restrict__ src, const int* __restrict__ dst,
                                 const float* __restrict__ dinv,
                                 int* __restrict__ cursor, u64* __restrict__ colw) {
    int part = blockIdx.x & (NPART - 1);
    int chunk = blockIdx.x >> 3;
    int e = chunk * FILL_EPB + threadIdx.x * 4;
    int lo = part * PART_NODES;
    int hi = lo + PART_NODES;
    if (e + 3 < N_EDGES) {
        int4 s4 = *(const int4*)(src + e);
        int4 d4 = *(const int4*)(dst + e);
        if (d4.x >= lo && d4.x < hi) {
            int p = atomicAdd(&cursor[d4.x], 1);
            colw[p] = pack_cw((unsigned)s4.x, dinv[s4.x]);
        }
        if (d4.y >= lo && d4.y < hi) {
            int p = atomicAdd(&cursor[d4.y], 1);
            colw[p] = pack_cw((unsigned)s4.y, dinv[s4.y]);
        }
        if (d4.z >= lo && d4.z < hi) {
            int p = atomicAdd(&cursor[d4.z], 1);
            colw[p] = pack_cw((unsigned)s4.z, dinv[s4.z]);
        }
        if (d4.w >= lo && d4.w < hi) {
            int p = atomicAdd(&cursor[d4.w], 1);
            colw[p] = pack_cw((unsigned)s4.w, dinv[s4.w]);
        }
    }
}

// ---- propagation: one wave per destination row, lane = embedding dim ----
// Lane-parallel colw fetch (one 8B/lane load covers the row), __shfl broadcast
// per edge, fp16 gathers (128B/wave), fp32 accumulate.
// FINAL layer fuses out = (emb + x1 + x2 + acc) * 0.25.
template <bool FINAL>
__global__ void gather_kernel(const int* __restrict__ row_start, const u64* __restrict__ colw,
                              const float* __restrict__ dinv,
                              const f16* __restrict__ xin, f16* __restrict__ xout,
                              const float* __restrict__ emb,
                              const f16* __restrict__ x1, const f16* __restrict__ x2,
                              float* __restrict__ out) {
    unsigned int gid = blockIdx.x * blockDim.x + threadIdx.x;
    unsigned int row = gid >> 6;
    int d = (int)(gid & 63u);  // lane == embedding dim
    if (row >= N_NODES) return;
    int beg = row_start[row];
    int end = row_start[row + 1];
    float acc = 0.0f;
    for (int cb = beg; cb < end; cb += 64) {
        // lane l holds edge cb+l of this row (clamped; excess lanes unused)
        int idx = cb + d;
        u64 pv = colw[idx < N_EDGES ? idx : (N_EDGES - 1)];
        unsigned ci = (unsigned)(pv & 0xffffffffu);
        float wi = __uint_as_float((unsigned)(pv >> 32));
        int n = end - cb;
        if (n > 64) n = 64;
        int k = 0;
        for (; k + 3 < n; k += 4) {
            unsigned c0 = (unsigned)__shfl((int)ci, k);
            unsigned c1 = (unsigned)__shfl((int)ci, k + 1);
            unsigned c2 = (unsigned)__shfl((int)ci, k + 2);
            unsigned c3 = (unsigned)__shfl((int)ci, k + 3);
            float w0 = __shfl(wi, k);
            float w1 = __shfl(wi, k + 1);
            float w2 = __shfl(wi, k + 2);
            float w3 = __shfl(wi, k + 3);
            float v0 = (float)xin[c0 * EMB + d];
            float v1 = (float)xin[c1 * EMB + d];
            float v2 = (float)xin[c2 * EMB + d];
            float v3 = (float)xin[c3 * EMB + d];
            acc += w0 * v0;
            acc += w1 * v1;
            acc += w2 * v2;
            acc += w3 * v3;
        }
        for (; k < n; ++k) {
            unsigned c = (unsigned)__shfl((int)ci, k);
            float w = __shfl(wi, k);
            acc += w * (float)xin[c * EMB + d];
        }
    }
    acc *= dinv[row];
    unsigned int o = row * EMB + (unsigned)d;
    if (!FINAL) {
        __builtin_nontemporal_store((f16)acc, &xout[o]);
    } else {
        float r = (emb[o] + (float)x1[o] + (float)x2[o] + acc) * 0.25f;
        __builtin_nontemporal_store(r, &out[o]);
    }
}

extern "C" void kernel_launch(void* const* d_in, const int* in_sizes, int n_in,
                              void* d_out, int out_size, void* d_ws, size_t ws_size,
                              hipStream_t stream) {
    const int*   edge = (const int*)d_in[0];   // (2, N_EDGES) row-major
    const int*   src  = edge;
    const int*   dst  = edge + N_EDGES;
    const float* emb  = (const float*)d_in[1]; // (N_NODES, 64) fp32
    float*       out  = (float*)d_out;

    // workspace carve (16B-aligned offsets), ~50 MB total
    char* ws = (char*)d_ws;
    size_t off = 0;
    int* deg       = (int*)(ws + off); off += 400000;  // reused as cursor
    int* row_start = (int*)(ws + off); off += 400016;
    int* bsums     = (int*)(ws + off); off += 512;
    float* dinv    = (float*)(ws + off); off += 400000;
    u64* colw      = (u64*)(ws + off); off += (size_t)N_EDGES * 8;         // 10.24 MB
    f16* x0h       = (f16*)(ws + off); off += (size_t)N_NODES * EMB * 2;   // 12.8 MB
    f16* x1h       = (f16*)(ws + off); off += (size_t)N_NODES * EMB * 2;   // 12.8 MB
    f16* x2h       = (f16*)(ws + off); off += (size_t)N_NODES * EMB * 2;   // 12.8 MB

    const int NB = (N_NODES + SCAN_TILE - 1) / SCAN_TILE;  // 98

    // ---- CSR build (once per call; reused by all 3 layers) ----
    hipMemsetAsync(deg, 0, (size_t)N_NODES * sizeof(int), stream);
    deg_kernel<<<(N_EDGES / 4 + 255) / 256, 256, 0, stream>>>(dst, deg);
    dinv_kernel<<<(N_NODES + 255) / 256, 256, 0, stream>>>(deg, dinv);
    scan1_kernel<<<NB, 256, 0, stream>>>(deg, row_start, bsums);
    scan2_kernel<<<1, 128, 0, stream>>>(bsums, NB);
    scan3_kernel<<<(N_NODES + 255) / 256, 256, 0, stream>>>(row_start, bsums, deg /*cursor*/);
    fill_part_kernel<<<(N_EDGES / FILL_EPB) * NPART, 256, 0, stream>>>(src, dst, dinv,
                                                                      deg /*cursor*/, colw);

    // ---- emb -> fp16 ----
    half_kernel<<<(N_NODES * EMB / 4 + 255) / 256, 256, 0, stream>>>(emb, x0h);

    // ---- 3 propagation layers (fp16 x), final fuses the 1/4-sum ----
    const unsigned int gthreads = (unsigned int)N_NODES * EMB;
    const int gblocks = (int)((gthreads + 255) / 256);
    gather_kernel<false><<<gblocks, 256, 0, stream>>>(row_start, colw, dinv, x0h, x1h,
                                                      emb, x1h, x2h, out);
    gather_kernel<false><<<gblocks, 256, 0, stream>>>(row_start, colw, dinv, x1h, x2h,
                                                      emb, x1h, x2h, out);
    gather_kernel<true><<<gblocks, 256, 0, stream>>>(row_start, colw, dinv, x2h, (f16*)0,
                                                     emb, x1h, x2h, out);
}